// Round 15
// baseline (89.638 us; speedup 1.0000x reference)
//
#include <hip/hip_runtime.h>
#include <hip/hip_bf16.h>
#include <math.h>

// Conditional_Embedding_Contrastive_loss on MI355X (gfx950)
// R12: half-tile blocks. Each 128x128 upper-tri tile splits into 2 blocks
//      (64x128, h=row-half) -> 1056 blocks x 256 thr = 4.125 independent
//      streams/CU (R4's proven anti-phased overlap) on the symmetric workload.
//      BK=64, LDS 24KB. Atomic-free epilogue -> 64 zeroed scratch slots.

#define NN   4096
#define DD   1024
#define NCLS 1000
#define EPSF 1e-8f
#define MW   (NN / 32)   // 128 mask words per class row
#define NTILE 528        // 32*33/2 upper-tri 128x128 tiles
#define NBLK  1056       // 2 half-blocks per tile
#define SLOTS 64

typedef short bf16x8 __attribute__((ext_vector_type(8)));
typedef float f32x4  __attribute__((ext_vector_type(4)));

// ---------- kernel 0: bit-pack cls_mask + labels + zero scratch (fused) ----------
__global__ __launch_bounds__(256) void k_pack(const int* __restrict__ cmask,
                                              const int* __restrict__ lraw,
                                              unsigned int* __restrict__ mbits,
                                              int* __restrict__ lab,
                                              float4* __restrict__ scrz) {
  const int b = blockIdx.x;
  if (b < NCLS * MW / 256) {             // 500 pack blocks
    const int wword = b * 256 + threadIdx.x;
    const int* src = cmask + (size_t)wword * 32;
    unsigned int v = 0;
    #pragma unroll
    for (int q = 0; q < 8; ++q) {
      const int4 c = *(const int4*)(src + q * 4);
      v |= (c.x != 0 ? 1u : 0u) << (q * 4 + 0);
      v |= (c.y != 0 ? 1u : 0u) << (q * 4 + 1);
      v |= (c.z != 0 ? 1u : 0u) << (q * 4 + 2);
      v |= (c.w != 0 ? 1u : 0u) << (q * 4 + 3);
    }
    mbits[wword] = v;
  } else if (b < NCLS * MW / 256 + NN / 256) {  // 16 label blocks
    __shared__ int stride_s;
    if (threadIdx.x == 0) {
      int stride = 2;  // assume int64 (little-endian)
      #pragma unroll
      for (int t = 0; t < 8; ++t) {
        int lo = lraw[2 * t], hi = lraw[2 * t + 1];
        if (hi != 0 || (unsigned)lo >= (unsigned)NCLS) { stride = 1; break; }
      }
      stride_s = stride;
    }
    __syncthreads();
    const int i = (b - NCLS * MW / 256) * 256 + threadIdx.x;
    lab[i] = lraw[i * stride_s];
  } else {                                // 1024 zero blocks: 4MB scratch
    const int zb = b - (NCLS * MW / 256 + NN / 256);
    scrz[(size_t)zb * 256 + threadIdx.x] = (float4){0.f, 0.f, 0.f, 0.f};
  }
}

// ---------- kernel 1: per-row norms, inst2embed_pos, f32->bf16 pack ----------
__global__ __launch_bounds__(256) void k_rowstats(
    const float* __restrict__ X, const float* __restrict__ A,
    const float* __restrict__ Tp, ushort* __restrict__ Xb,
    float* __restrict__ rnx, float* __restrict__ rnT,
    float* __restrict__ epos, float* __restrict__ out) {
  const int i = blockIdx.x;
  const int t = threadIdx.x;
  const size_t base = (size_t)i * DD + t * 4;
  const float4 xv = *(const float4*)(X + base);
  const float4 av = *(const float4*)(A + base);
  float sxx = xv.x * xv.x + xv.y * xv.y + xv.z * xv.z + xv.w * xv.w;
  float saa = av.x * av.x + av.y * av.y + av.z * av.z + av.w * av.w;
  float sxa = xv.x * av.x + xv.y * av.y + xv.z * av.z + xv.w * av.w;

  ushort4 pk;
  { __hip_bfloat16 b;
    b = __float2bfloat16(xv.x); pk.x = *(const ushort*)&b;
    b = __float2bfloat16(xv.y); pk.y = *(const ushort*)&b;
    b = __float2bfloat16(xv.z); pk.z = *(const ushort*)&b;
    b = __float2bfloat16(xv.w); pk.w = *(const ushort*)&b; }
  *(ushort4*)(Xb + base) = pk;

  #pragma unroll
  for (int off = 32; off > 0; off >>= 1) {
    sxx += __shfl_down(sxx, off);
    saa += __shfl_down(saa, off);
    sxa += __shfl_down(sxa, off);
  }
  __shared__ float red[3][4];
  const int w = t >> 6;
  if ((t & 63) == 0) { red[0][w] = sxx; red[1][w] = saa; red[2][w] = sxa; }
  __syncthreads();
  if (t == 0) {
    const float a  = red[0][0] + red[0][1] + red[0][2] + red[0][3];
    const float bb = red[1][0] + red[1][1] + red[1][2] + red[1][3];
    const float c  = red[2][0] + red[2][1] + red[2][2] + red[2][3];
    const float nxi = sqrtf(a), nai = sqrtf(bb);
    const float rT  = 1.0f / Tp[0];
    const float r   = 1.0f / fmaxf(nxi, 1e-20f);
    rnx[i] = r;
    rnT[i] = r * rT;
    epos[i] = expf((c / fmaxf(nxi * nai, EPSF)) * rT);
    if (i == 0) out[0] = 0.f;
  }
}

// ---------- kernel 2: symmetric fused Gram, 64x128 half-tile blocks ----------
#define BK 64
// LDS: A [64][64] bf16 (8KB) + B [128][64] bf16 (16KB). XOR swizzle
// phys slot = logical ^ (row&7), pre-swizzled on the GLOBAL source.

__global__ __launch_bounds__(256, 4) void k_gram(
    const ushort* __restrict__ Xb, const float* __restrict__ rnx,
    const float* __restrict__ rnT,
    const int* __restrict__ lab, const unsigned int* __restrict__ mbits,
    float* __restrict__ scrF, float* __restrict__ scrM) {
  __shared__ __align__(16) char As[64 * 128];    // 8 KB
  __shared__ __align__(16) char Bs[128 * 128];   // 16 KB
  const int tid  = threadIdx.x;
  const int lane = tid & 63;
  const int w    = tid >> 6;       // wave 0..3

  // tile decode: blk = tile*2 + h; XCD-aware on tile (xcd = tile&7).
  const int h    = blockIdx.x & 1;
  const int tile = blockIdx.x >> 1;
  const int xcd  = tile & 7;
  const int l    = tile >> 3;               // 0..65
  const int p    = (xcd << 1) + (l >= 33);  // pair index
  const int q    = (l >= 33) ? (l - 33) : l;
  int by, bx;
  if (q < 32 - p) { by = p;      bx = p + q; }
  else            { by = 31 - p; bx = 31 - p + (q - (32 - p)); }
  const bool offdiag = (bx != by);
  const int i0h = by * 128 + h * 64;        // this block's 64 A-rows
  const int j0  = bx * 128;

  const int sslot = (lane & 7) ^ (lane >> 3);  // pre-swizzled global k-slot

  f32x4 acc[4][2];
  #pragma unroll
  for (int m = 0; m < 4; ++m)
    #pragma unroll
    for (int n = 0; n < 2; ++n)
      acc[m][n] = (f32x4){0.f, 0.f, 0.f, 0.f};

  // staging sources: A 2 chunks (wave rows w*16+q*8), B 4 chunks (w*32+q*8)
  const ushort* pA[2];
  const ushort* pB[4];
  #pragma unroll
  for (int q2 = 0; q2 < 2; ++q2)
    pA[q2] = Xb + (size_t)(i0h + (w << 4) + (q2 << 3) + (lane >> 3)) * DD + sslot * 8;
  #pragma unroll
  for (int q2 = 0; q2 < 4; ++q2)
    pB[q2] = Xb + (size_t)(j0 + (w << 5) + (q2 << 3) + (lane >> 3)) * DD + sslot * 8;

  for (int k0 = 0; k0 < DD; k0 += BK) {
    #pragma unroll
    for (int q2 = 0; q2 < 2; ++q2)
      __builtin_amdgcn_global_load_lds(
          (const __attribute__((address_space(1))) void*)(pA[q2] + k0),
          (__attribute__((address_space(3))) void*)(As + ((w << 1) + q2) * 1024), 16, 0, 0);
    #pragma unroll
    for (int q2 = 0; q2 < 4; ++q2)
      __builtin_amdgcn_global_load_lds(
          (const __attribute__((address_space(1))) void*)(pB[q2] + k0),
          (__attribute__((address_space(3))) void*)(Bs + ((w << 2) + q2) * 1024), 16, 0, 0);
    __syncthreads();

    #pragma unroll
    for (int ks = 0; ks < 2; ++ks) {
      const int slot = ((ks << 2) + (lane >> 4)) ^ (lane & 7);
      bf16x8 af[4], bfr[2];
      #pragma unroll
      for (int m = 0; m < 4; ++m) {
        const int r = (m << 4) + (lane & 15);
        af[m] = *(const bf16x8*)(As + r * 128 + (slot << 4));
      }
      #pragma unroll
      for (int n = 0; n < 2; ++n) {
        const int r = (w << 5) + (n << 4) + (lane & 15);
        bfr[n] = *(const bf16x8*)(Bs + r * 128 + (slot << 4));
      }
      #pragma unroll
      for (int m = 0; m < 4; ++m)
        #pragma unroll
        for (int n = 0; n < 2; ++n)
          acc[m][n] = __builtin_amdgcn_mfma_f32_16x16x32_bf16(af[m], bfr[n], acc[m][n], 0, 0, 0);
    }
    __syncthreads();
  }

  // ---- epilogue (atomic-free). C/D map: col=lane&15, row=(lane>>4)*4+reg.
  // Wave sub-tile: all 64 rows x cols [w*32, w*32+32).
  float* LF = (float*)As;          // i-side sfull partials [w][64] = 256
  float* LM = LF + 256;            // i-side smask
  float* GF = LM + 256;            // j-side sfull [128]
  float* GM = GF + 128;            // j-side smask

  float rnT_j[2];
  unsigned long long wj[2];        // mask row lab[j_n] over this block's 64 i-rows
  #pragma unroll
  for (int n = 0; n < 2; ++n) {
    const int j = j0 + (w << 5) + (n << 4) + (lane & 15);
    rnT_j[n] = rnT[j];
    wj[n] = *(const unsigned long long*)(mbits + (size_t)lab[j] * MW + (i0h >> 5));
  }
  float pse[2] = {0.f, 0.f}, psm[2] = {0.f, 0.f};

  #pragma unroll
  for (int m = 0; m < 4; ++m) {
    #pragma unroll
    for (int r = 0; r < 4; ++r) {
      const int irow = (m << 4) + ((lane >> 4) << 2) + r;    // 0..63
      const int i = i0h + irow;
      const float rni = rnx[i];
      const unsigned int wi = mbits[(size_t)lab[i] * MW + (j0 >> 5) + w];  // wave's 32-col span
      float se = 0.f, sm = 0.f;
      #pragma unroll
      for (int n = 0; n < 2; ++n) {
        const int j = j0 + (w << 5) + (n << 4) + (lane & 15);
        float e = __expf(acc[m][n][r] * rni * rnT_j[n]);
        if (i == j) e = 0.f;                                 // remove_diag
        se += e;
        const int bposj = (n << 4) + (lane & 15);            // 0..31
        sm += ((wi >> bposj) & 1u) ? e : 0.f;
        pse[n] += e;
        psm[n] += ((wj[n] >> irow) & 1ull) ? e : 0.f;
      }
      #pragma unroll
      for (int off = 1; off < 16; off <<= 1) {
        se += __shfl_xor(se, off);
        sm += __shfl_xor(sm, off);
      }
      if ((lane & 15) == 0) {                                // lanes 0,16,32,48
        LF[(w << 6) + irow] = se;
        LM[(w << 6) + irow] = sm;
      }
    }
  }
  if (offdiag) {
    #pragma unroll
    for (int n = 0; n < 2; ++n) {
      float se = pse[n], sm = psm[n];
      se += __shfl_xor(se, 16); se += __shfl_xor(se, 32);
      sm += __shfl_xor(sm, 16); sm += __shfl_xor(sm, 32);
      if (lane < 16) {
        GF[(w << 5) + (n << 4) + lane] = se;
        GM[(w << 5) + (n << 4) + lane] = sm;
      }
    }
  }
  __syncthreads();

  // combine + coalesced stores. Slots: i-side -> h*32+bx (64 rows at i0h);
  // j-side -> h*32+by (128 rows at j0). Unwritten slot entries are pre-zeroed.
  if (tid < 64) {
    scrF[(size_t)(h * 32 + bx) * NN + i0h + tid] =
        LF[tid] + LF[64 + tid] + LF[128 + tid] + LF[192 + tid];
  } else if (tid < 128) {
    const int u = tid - 64;
    scrM[(size_t)(h * 32 + bx) * NN + i0h + u] =
        LM[u] + LM[64 + u] + LM[128 + u] + LM[192 + u];
  } else if (offdiag) {
    const int u = tid - 128;
    scrF[(size_t)(h * 32 + by) * NN + j0 + u] = GF[u];
    scrM[(size_t)(h * 32 + by) * NN + j0 + u] = GM[u];
  }
}

// ---------- kernel 3: loss = mean(log(den) - log(num)) ----------
__global__ __launch_bounds__(256) void k_final(
    const float* __restrict__ scrF, const float* __restrict__ scrM,
    const float* __restrict__ epos, float* __restrict__ out) {
  const int idx = blockIdx.x * 256 + threadIdx.x;
  float sf = 0.f, sm = 0.f;
  #pragma unroll
  for (int s = 0; s < SLOTS; ++s) {
    sf += scrF[(size_t)s * NN + idx];
    sm += scrM[(size_t)s * NN + idx];
  }
  const float ep  = epos[idx];
  const float num = sm + ep;
  const float den = ep + sf;
  float v = (logf(den) - logf(num)) * (1.0f / (float)NN);
  #pragma unroll
  for (int off = 32; off > 0; off >>= 1) v += __shfl_down(v, off);
  __shared__ float red[4];
  if ((threadIdx.x & 63) == 0) red[threadIdx.x >> 6] = v;
  __syncthreads();
  if (threadIdx.x == 0) atomicAdd(out, red[0] + red[1] + red[2] + red[3]);
}

extern "C" void kernel_launch(void* const* d_in, const int* in_sizes, int n_in,
                              void* d_out, int out_size, void* d_ws, size_t ws_size,
                              hipStream_t stream) {
  const float* X     = (const float*)d_in[0];
  const float* A     = (const float*)d_in[1];
  const int*   cmask = (const int*)d_in[2];
  const int*   lraw  = (const int*)d_in[3];
  const float* Tp    = (const float*)d_in[4];
  float* out = (float*)d_out;

  char* ws = (char*)d_ws;
  ushort* Xb   = (ushort*)ws;                          // 8 MB
  float* rnx   = (float*)(ws + (size_t)NN * DD * 2);
  float* rnT   = rnx + NN;
  float* epos  = rnT + NN;
  int*   lab   = (int*)(epos + NN);
  unsigned int* mbits = (unsigned int*)(lab + NN);     // 512 KB
  float* scrF  = (float*)(mbits + (size_t)NCLS * MW);  // 1 MB (64 slots)
  float* scrM  = scrF + (size_t)SLOTS * NN;            // 1 MB

  const int packg = NCLS * MW / 256 + NN / 256 + 1024; // pack + labels + zero

  hipLaunchKernelGGL(k_pack,     dim3(packg),  dim3(256), 0, stream, cmask, lraw, mbits, lab, (float4*)scrF);
  hipLaunchKernelGGL(k_rowstats, dim3(NN),     dim3(256), 0, stream, X, A, Tp, Xb, rnx, rnT, epos, out);
  hipLaunchKernelGGL(k_gram,     dim3(NBLK),   dim3(256), 0, stream, Xb, rnx, rnT, lab, mbits, scrF, scrM);
  hipLaunchKernelGGL(k_final,    dim3(NN/256), dim3(256), 0, stream, scrF, scrM, epos, out);
}

// Round 17
// 78.897 us; speedup vs baseline: 1.1361x; 1.1361x over previous
//
#include <hip/hip_runtime.h>
#include <hip/hip_bf16.h>
#include <math.h>

// Conditional_Embedding_Contrastive_loss on MI355X (gfx950)
// R13: R11 base (8-wave 128x128 tiles, XCD map, atomic-free epilogue) +
//      T4 counted-vmcnt pipeline: BK=64 double-buffer, stage(s+1) issued
//      before compute(s), s_waitcnt vmcnt(4) + raw s_barrier (loads stay in
//      flight ACROSS barriers; never drain to 0 in the loop).

#define NN   4096
#define DD   1024
#define NCLS 1000
#define EPSF 1e-8f
#define MW   (NN / 32)   // 128 mask words per class row
#define NTILE 528        // 32*33/2 upper-tri 128x128 tiles
#define SLOTS 32

typedef short bf16x8 __attribute__((ext_vector_type(8)));
typedef float f32x4  __attribute__((ext_vector_type(4)));

// ---------- kernel 0: bit-pack cls_mask + compact labels (fused) ----------
__global__ __launch_bounds__(256) void k_pack(const int* __restrict__ cmask,
                                              const int* __restrict__ lraw,
                                              unsigned int* __restrict__ mbits,
                                              int* __restrict__ lab) {
  const int b = blockIdx.x;
  if (b < NCLS * MW / 256) {             // 500 pack blocks
    const int wword = b * 256 + threadIdx.x;
    const int* src = cmask + (size_t)wword * 32;
    unsigned int v = 0;
    #pragma unroll
    for (int q = 0; q < 8; ++q) {
      const int4 c = *(const int4*)(src + q * 4);
      v |= (c.x != 0 ? 1u : 0u) << (q * 4 + 0);
      v |= (c.y != 0 ? 1u : 0u) << (q * 4 + 1);
      v |= (c.z != 0 ? 1u : 0u) << (q * 4 + 2);
      v |= (c.w != 0 ? 1u : 0u) << (q * 4 + 3);
    }
    mbits[wword] = v;
  } else {                                // 16 label blocks
    __shared__ int stride_s;
    if (threadIdx.x == 0) {
      int stride = 2;  // assume int64 (little-endian)
      #pragma unroll
      for (int t = 0; t < 8; ++t) {
        int lo = lraw[2 * t], hi = lraw[2 * t + 1];
        if (hi != 0 || (unsigned)lo >= (unsigned)NCLS) { stride = 1; break; }
      }
      stride_s = stride;
    }
    __syncthreads();
    const int i = (b - NCLS * MW / 256) * 256 + threadIdx.x;
    lab[i] = lraw[i * stride_s];
  }
}

// ---------- kernel 1: per-row norms, inst2embed_pos, f32->bf16 pack ----------
__global__ __launch_bounds__(256) void k_rowstats(
    const float* __restrict__ X, const float* __restrict__ A,
    const float* __restrict__ Tp, ushort* __restrict__ Xb,
    float* __restrict__ rnx, float* __restrict__ rnT,
    float* __restrict__ epos, float* __restrict__ out) {
  const int i = blockIdx.x;
  const int t = threadIdx.x;
  const size_t base = (size_t)i * DD + t * 4;
  const float4 xv = *(const float4*)(X + base);
  const float4 av = *(const float4*)(A + base);
  float sxx = xv.x * xv.x + xv.y * xv.y + xv.z * xv.z + xv.w * xv.w;
  float saa = av.x * av.x + av.y * av.y + av.z * av.z + av.w * av.w;
  float sxa = xv.x * av.x + xv.y * av.y + xv.z * av.z + xv.w * av.w;

  ushort4 pk;
  { __hip_bfloat16 b;
    b = __float2bfloat16(xv.x); pk.x = *(const ushort*)&b;
    b = __float2bfloat16(xv.y); pk.y = *(const ushort*)&b;
    b = __float2bfloat16(xv.z); pk.z = *(const ushort*)&b;
    b = __float2bfloat16(xv.w); pk.w = *(const ushort*)&b; }
  *(ushort4*)(Xb + base) = pk;

  #pragma unroll
  for (int off = 32; off > 0; off >>= 1) {
    sxx += __shfl_down(sxx, off);
    saa += __shfl_down(saa, off);
    sxa += __shfl_down(sxa, off);
  }
  __shared__ float red[3][4];
  const int w = t >> 6;
  if ((t & 63) == 0) { red[0][w] = sxx; red[1][w] = saa; red[2][w] = sxa; }
  __syncthreads();
  if (t == 0) {
    const float a  = red[0][0] + red[0][1] + red[0][2] + red[0][3];
    const float bb = red[1][0] + red[1][1] + red[1][2] + red[1][3];
    const float c  = red[2][0] + red[2][1] + red[2][2] + red[2][3];
    const float nxi = sqrtf(a), nai = sqrtf(bb);
    const float rT  = 1.0f / Tp[0];
    const float r   = 1.0f / fmaxf(nxi, 1e-20f);
    rnx[i] = r;
    rnT[i] = r * rT;
    epos[i] = expf((c / fmaxf(nxi * nai, EPSF)) * rT);
    if (i == 0) out[0] = 0.f;
  }
}

// ---------- kernel 2: symmetric fused Gram, counted-vmcnt dbuf pipeline ----------
#define BM 128
#define BK 64
#define NSTEP (DD / BK)   // 16
// LDS: 2 buffers x (A [128][64] + B [128][64]) bf16 = 2 x 32KB.
// XOR swizzle phys slot = logical ^ (row&7), pre-swizzled on GLOBAL source.

__global__ __launch_bounds__(512, 4) void k_gram(
    const ushort* __restrict__ Xb, const float* __restrict__ rnx,
    const float* __restrict__ rnT,
    const int* __restrict__ lab, const unsigned int* __restrict__ mbits,
    float* __restrict__ scrF, float* __restrict__ scrM) {
  __shared__ __align__(16) char LDS[2 * 2 * BM * 64 * 2];   // 64 KB
  const int tid  = threadIdx.x;
  const int lane = tid & 63;
  const int w    = tid >> 6;       // wave 0..7
  const int wr   = w >> 2;         // 0..1 : 64-row half
  const int wc   = w & 3;          // 0..3 : 32-col quarter

  // XCD-aware tile decode: xcd = blk%8 owns row-pairs {2x, 2x+1}.
  const int xcd = blockIdx.x & 7;
  const int l   = blockIdx.x >> 3;          // 0..65
  const int p   = (xcd << 1) + (l >= 33);   // pair index
  const int q   = (l >= 33) ? (l - 33) : l; // 0..32 within pair
  int by, bx;
  if (q < 32 - p) { by = p;      bx = p + q; }
  else            { by = 31 - p; bx = 31 - p + (q - (32 - p)); }
  const bool offdiag = (bx != by);
  const int i0 = by * BM;
  const int j0 = bx * BM;

  const int sslot = (lane & 7) ^ (lane >> 3);  // pre-swizzled global k-slot

  f32x4 acc[4][2];
  #pragma unroll
  for (int m = 0; m < 4; ++m)
    #pragma unroll
    for (int n = 0; n < 2; ++n)
      acc[m][n] = (f32x4){0.f, 0.f, 0.f, 0.f};

  // staging: wave w covers rows [w*16, w*16+16) of A and of B; 2 chunks each.
  const ushort* pA[2];
  const ushort* pB[2];
  #pragma unroll
  for (int q2 = 0; q2 < 2; ++q2) {
    const int row = (w << 4) + (q2 << 3) + (lane >> 3);
    pA[q2] = Xb + (size_t)(i0 + row) * DD + sslot * 8;
    pB[q2] = Xb + (size_t)(j0 + row) * DD + sslot * 8;
  }

  // STAGE(buf, k): 4 gload_lds per wave (A 2 chunks, B 2 chunks)
  #define STAGE(BUF, K0)                                                        \
    {                                                                           \
      char* Ad = LDS + (BUF) * 32768;                                           \
      char* Bd = Ad + 16384;                                                    \
      _Pragma("unroll")                                                         \
      for (int q2 = 0; q2 < 2; ++q2) {                                          \
        const int ldo = ((w << 1) + q2) * 1024;                                 \
        __builtin_amdgcn_global_load_lds(                                       \
            (const __attribute__((address_space(1))) void*)(pA[q2] + (K0)),     \
            (__attribute__((address_space(3))) void*)(Ad + ldo), 16, 0, 0);     \
        __builtin_amdgcn_global_load_lds(                                       \
            (const __attribute__((address_space(1))) void*)(pB[q2] + (K0)),     \
            (__attribute__((address_space(3))) void*)(Bd + ldo), 16, 0, 0);     \
      }                                                                         \
    }

  // prologue: stage step 0 into buffer 0
  STAGE(0, 0)

  for (int s = 0; s < NSTEP; ++s) {
    const int cur = s & 1;
    if (s + 1 < NSTEP) {
      STAGE(cur ^ 1, (s + 1) * BK)
      // wait for stage(s) (4 newer loads = stage(s+1) still in flight), join waves
      asm volatile("s_waitcnt vmcnt(4)\n\ts_barrier" ::: "memory");
    } else {
      asm volatile("s_waitcnt vmcnt(0)\n\ts_barrier" ::: "memory");
    }

    const char* Ab = LDS + cur * 32768;
    const char* Bb = Ab + 16384;
    #pragma unroll
    for (int ks = 0; ks < 2; ++ks) {
      const int slot = ((ks << 2) + (lane >> 4)) ^ (lane & 7);
      bf16x8 af[4], bfr[2];
      #pragma unroll
      for (int m = 0; m < 4; ++m) {
        const int r = (wr << 6) + (m << 4) + (lane & 15);
        af[m] = *(const bf16x8*)(Ab + r * 128 + (slot << 4));
      }
      #pragma unroll
      for (int n = 0; n < 2; ++n) {
        const int r = (wc << 5) + (n << 4) + (lane & 15);
        bfr[n] = *(const bf16x8*)(Bb + r * 128 + (slot << 4));
      }
      #pragma unroll
      for (int m = 0; m < 4; ++m)
        #pragma unroll
        for (int n = 0; n < 2; ++n)
          acc[m][n] = __builtin_amdgcn_mfma_f32_16x16x32_bf16(af[m], bfr[n], acc[m][n], 0, 0, 0);
    }
    // protect buf[cur]: all waves must finish their ds_reads before step s+1's
    // STAGE (which targets buf[cur]) can overwrite it.
    asm volatile("s_barrier" ::: "memory");
  }

  // ---- epilogue (atomic-free). C/D map: col=lane&15, row=(lane>>4)*4+reg.
  // Wave sub-tile: rows [wr*64, +64), cols [wc*32, +32). LDS reuse is safe:
  // final in-loop barrier retired all K-loop LDS reads.
  float* LF = (float*)LDS;         // i-side sfull partials [wc][wr][64] = 512
  float* LM = LF + 512;            // i-side smask
  float* GF = LM + 512;            // j-side sfull [wr][128] = 256
  float* GM = GF + 256;            // j-side smask

  float rnT_j[2];
  unsigned long long wj[2];        // mask row lab[j_n], 64 bits over wave's i-span
  #pragma unroll
  for (int n = 0; n < 2; ++n) {
    const int j = j0 + (wc << 5) + (n << 4) + (lane & 15);
    rnT_j[n] = rnT[j];
    wj[n] = *(const unsigned long long*)(mbits + (size_t)lab[j] * MW + (i0 >> 5) + (wr << 1));
  }
  float pse[2] = {0.f, 0.f}, psm[2] = {0.f, 0.f};

  #pragma unroll
  for (int m = 0; m < 4; ++m) {
    #pragma unroll
    for (int r = 0; r < 4; ++r) {
      const int irow = (m << 4) + ((lane >> 4) << 2) + r;    // 0..63 in wave's row-half
      const int i = i0 + (wr << 6) + irow;
      const float rni = rnx[i];
      const unsigned int wi = mbits[(size_t)lab[i] * MW + (j0 >> 5) + wc];  // wave's 32-col span
      float se = 0.f, sm = 0.f;
      #pragma unroll
      for (int n = 0; n < 2; ++n) {
        const int j = j0 + (wc << 5) + (n << 4) + (lane & 15);
        float e = __expf(acc[m][n][r] * rni * rnT_j[n]);
        if (i == j) e = 0.f;                                 // remove_diag
        se += e;
        const int bposj = (n << 4) + (lane & 15);            // 0..31
        sm += ((wi >> bposj) & 1u) ? e : 0.f;
        pse[n] += e;
        psm[n] += ((wj[n] >> irow) & 1ull) ? e : 0.f;
      }
      #pragma unroll
      for (int off = 1; off < 16; off <<= 1) {
        se += __shfl_xor(se, off);
        sm += __shfl_xor(sm, off);
      }
      if ((lane & 15) == 0) {                                // lanes 0,16,32,48
        LF[(wc << 7) + (wr << 6) + irow] = se;
        LM[(wc << 7) + (wr << 6) + irow] = sm;
      }
    }
  }
  if (offdiag) {
    #pragma unroll
    for (int n = 0; n < 2; ++n) {
      float se = pse[n], sm = psm[n];
      se += __shfl_xor(se, 16); se += __shfl_xor(se, 32);
      sm += __shfl_xor(sm, 16); sm += __shfl_xor(sm, 32);
      if (lane < 16) {
        GF[(wr << 7) + (wc << 5) + (n << 4) + lane] = se;
        GM[(wr << 7) + (wc << 5) + (n << 4) + lane] = sm;
      }
    }
  }
  __syncthreads();

  // cross-wave combine + coalesced stores. Slot ownership:
  //   i-side (rows i0..i0+127) -> slot bx ; j-side (rows j0..j0+127) -> slot by.
  if (tid < 128) {
    scrF[(size_t)bx * NN + i0 + tid] = LF[tid] + LF[128 + tid] + LF[256 + tid] + LF[384 + tid];
    if (offdiag) scrF[(size_t)by * NN + j0 + tid] = GF[tid] + GF[128 + tid];
  } else if (tid < 256) {
    const int u = tid - 128;
    scrM[(size_t)bx * NN + i0 + u] = LM[u] + LM[128 + u] + LM[256 + u] + LM[384 + u];
    if (offdiag) scrM[(size_t)by * NN + j0 + u] = GM[u] + GM[128 + u];
  }
}

// ---------- kernel 3: loss = mean(log(den) - log(num)) ----------
__global__ __launch_bounds__(256) void k_final(
    const float* __restrict__ scrF, const float* __restrict__ scrM,
    const float* __restrict__ epos, float* __restrict__ out) {
  const int idx = blockIdx.x * 256 + threadIdx.x;
  float sf = 0.f, sm = 0.f;
  #pragma unroll
  for (int s = 0; s < SLOTS; ++s) {
    sf += scrF[(size_t)s * NN + idx];
    sm += scrM[(size_t)s * NN + idx];
  }
  const float ep  = epos[idx];
  const float num = sm + ep;
  const float den = ep + sf;
  float v = (logf(den) - logf(num)) * (1.0f / (float)NN);
  #pragma unroll
  for (int off = 32; off > 0; off >>= 1) v += __shfl_down(v, off);
  __shared__ float red[4];
  if ((threadIdx.x & 63) == 0) red[threadIdx.x >> 6] = v;
  __syncthreads();
  if (threadIdx.x == 0) atomicAdd(out, red[0] + red[1] + red[2] + red[3]);
}

extern "C" void kernel_launch(void* const* d_in, const int* in_sizes, int n_in,
                              void* d_out, int out_size, void* d_ws, size_t ws_size,
                              hipStream_t stream) {
  const float* X     = (const float*)d_in[0];
  const float* A     = (const float*)d_in[1];
  const int*   cmask = (const int*)d_in[2];
  const int*   lraw  = (const int*)d_in[3];
  const float* Tp    = (const float*)d_in[4];
  float* out = (float*)d_out;

  char* ws = (char*)d_ws;
  ushort* Xb   = (ushort*)ws;                          // 8 MB
  float* rnx   = (float*)(ws + (size_t)NN * DD * 2);
  float* rnT   = rnx + NN;
  float* epos  = rnT + NN;
  int*   lab   = (int*)(epos + NN);
  unsigned int* mbits = (unsigned int*)(lab + NN);     // 512 KB
  float* scrF  = (float*)(mbits + (size_t)NCLS * MW);  // 512 KB
  float* scrM  = scrF + (size_t)SLOTS * NN;            // 512 KB

  hipLaunchKernelGGL(k_pack,     dim3(NCLS * MW / 256 + NN / 256), dim3(256), 0, stream, cmask, lraw, mbits, lab);
  hipLaunchKernelGGL(k_rowstats, dim3(NN),     dim3(256), 0, stream, X, A, Tp, Xb, rnx, rnT, epos, out);
  hipLaunchKernelGGL(k_gram,     dim3(NTILE),  dim3(512), 0, stream, Xb, rnx, rnT, lab, mbits, scrF, scrM);
  hipLaunchKernelGGL(k_final,    dim3(NN/256), dim3(256), 0, stream, scrF, scrM, epos, out);
}

// Round 19
// 77.088 us; speedup vs baseline: 1.1628x; 1.0235x over previous
//
#include <hip/hip_runtime.h>
#include <hip/hip_bf16.h>
#include <math.h>

// Conditional_Embedding_Contrastive_loss on MI355X (gfx950)
// R14: phase-split deep pipeline. BK=32, QUAD-buffered LDS (4x16KB); per phase:
//      stage tile t+3 (2 gload/thr) ; vmcnt(6)+s_barrier (3 tiles ALWAYS in
//      flight) ; 6 ds_read_b128 ; setprio(1) 8 MFMA setprio(0) ; s_barrier.
//      Tail: one vmcnt(0), then 3 barrier-free tiles. Epilogue = R13 verbatim.

#define NN   4096
#define DD   1024
#define NCLS 1000
#define EPSF 1e-8f
#define MW   (NN / 32)   // 128 mask words per class row
#define NTILE 528        // 32*33/2 upper-tri 128x128 tiles
#define SLOTS 32
#define NSTEP 32         // DD / 32

typedef short bf16x8 __attribute__((ext_vector_type(8)));
typedef float f32x4  __attribute__((ext_vector_type(4)));

// ---------- kernel 0: bit-pack cls_mask + compact labels (fused) ----------
__global__ __launch_bounds__(256) void k_pack(const int* __restrict__ cmask,
                                              const int* __restrict__ lraw,
                                              unsigned int* __restrict__ mbits,
                                              int* __restrict__ lab) {
  const int b = blockIdx.x;
  if (b < NCLS * MW / 256) {             // 500 pack blocks
    const int wword = b * 256 + threadIdx.x;
    const int* src = cmask + (size_t)wword * 32;
    unsigned int v = 0;
    #pragma unroll
    for (int q = 0; q < 8; ++q) {
      const int4 c = *(const int4*)(src + q * 4);
      v |= (c.x != 0 ? 1u : 0u) << (q * 4 + 0);
      v |= (c.y != 0 ? 1u : 0u) << (q * 4 + 1);
      v |= (c.z != 0 ? 1u : 0u) << (q * 4 + 2);
      v |= (c.w != 0 ? 1u : 0u) << (q * 4 + 3);
    }
    mbits[wword] = v;
  } else {                                // 16 label blocks
    __shared__ int stride_s;
    if (threadIdx.x == 0) {
      int stride = 2;  // assume int64 (little-endian)
      #pragma unroll
      for (int t = 0; t < 8; ++t) {
        int lo = lraw[2 * t], hi = lraw[2 * t + 1];
        if (hi != 0 || (unsigned)lo >= (unsigned)NCLS) { stride = 1; break; }
      }
      stride_s = stride;
    }
    __syncthreads();
    const int i = (b - NCLS * MW / 256) * 256 + threadIdx.x;
    lab[i] = lraw[i * stride_s];
  }
}

// ---------- kernel 1: per-row norms, inst2embed_pos, f32->bf16 pack ----------
__global__ __launch_bounds__(256) void k_rowstats(
    const float* __restrict__ X, const float* __restrict__ A,
    const float* __restrict__ Tp, ushort* __restrict__ Xb,
    float* __restrict__ rnx, float* __restrict__ rnT,
    float* __restrict__ epos, float* __restrict__ out) {
  const int i = blockIdx.x;
  const int t = threadIdx.x;
  const size_t base = (size_t)i * DD + t * 4;
  const float4 xv = *(const float4*)(X + base);
  const float4 av = *(const float4*)(A + base);
  float sxx = xv.x * xv.x + xv.y * xv.y + xv.z * xv.z + xv.w * xv.w;
  float saa = av.x * av.x + av.y * av.y + av.z * av.z + av.w * av.w;
  float sxa = xv.x * av.x + xv.y * av.y + xv.z * av.z + xv.w * av.w;

  ushort4 pk;
  { __hip_bfloat16 b;
    b = __float2bfloat16(xv.x); pk.x = *(const ushort*)&b;
    b = __float2bfloat16(xv.y); pk.y = *(const ushort*)&b;
    b = __float2bfloat16(xv.z); pk.z = *(const ushort*)&b;
    b = __float2bfloat16(xv.w); pk.w = *(const ushort*)&b; }
  *(ushort4*)(Xb + base) = pk;

  #pragma unroll
  for (int off = 32; off > 0; off >>= 1) {
    sxx += __shfl_down(sxx, off);
    saa += __shfl_down(saa, off);
    sxa += __shfl_down(sxa, off);
  }
  __shared__ float red[3][4];
  const int w = t >> 6;
  if ((t & 63) == 0) { red[0][w] = sxx; red[1][w] = saa; red[2][w] = sxa; }
  __syncthreads();
  if (t == 0) {
    const float a  = red[0][0] + red[0][1] + red[0][2] + red[0][3];
    const float bb = red[1][0] + red[1][1] + red[1][2] + red[1][3];
    const float c  = red[2][0] + red[2][1] + red[2][2] + red[2][3];
    const float nxi = sqrtf(a), nai = sqrtf(bb);
    const float rT  = 1.0f / Tp[0];
    const float r   = 1.0f / fmaxf(nxi, 1e-20f);
    rnx[i] = r;
    rnT[i] = r * rT;
    epos[i] = expf((c / fmaxf(nxi * nai, EPSF)) * rT);
    if (i == 0) out[0] = 0.f;
  }
}

// ---------- kernel 2: symmetric fused Gram, phase-split quad-buffer pipeline ----------
#define BM 128
// LDS buffer per K-tile (BK=32): A [128][32] bf16 (8KB) + B [128][32] (8KB).
// Row = 64 B = 4 x 16B slots. Swizzle: phys slot = logical ^ ((row>>1)&3),
// pre-applied on the GLOBAL source (gload_lds writes linearly).

__global__ __launch_bounds__(512, 4) void k_gram(
    const ushort* __restrict__ Xb, const float* __restrict__ rnx,
    const float* __restrict__ rnT,
    const int* __restrict__ lab, const unsigned int* __restrict__ mbits,
    float* __restrict__ scrF, float* __restrict__ scrM) {
  __shared__ __align__(16) char LDS[4 * 16384];   // 64 KB, quad-buffered
  const int tid  = threadIdx.x;
  const int lane = tid & 63;
  const int w    = tid >> 6;       // wave 0..7
  const int wr   = w >> 2;         // 0..1 : 64-row half
  const int wc   = w & 3;          // 0..3 : 32-col quarter

  // XCD-aware tile decode: xcd = blk%8 owns row-pairs {2x, 2x+1}.
  const int xcd = blockIdx.x & 7;
  const int l   = blockIdx.x >> 3;          // 0..65
  const int p   = (xcd << 1) + (l >= 33);   // pair index
  const int q   = (l >= 33) ? (l - 33) : l; // 0..32 within pair
  int by, bx;
  if (q < 32 - p) { by = p;      bx = p + q; }
  else            { by = 31 - p; bx = 31 - p + (q - (32 - p)); }
  const bool offdiag = (bx != by);
  const int i0 = by * BM;
  const int j0 = bx * BM;

  // staging source: lane l -> row (w*16 + l>>2), phys slot l&3 which must hold
  // logical k-slot qs = (l&3) ^ f(row), f(row)=(row>>1)&3 = (l>>3)&3.
  const int qs = (lane & 3) ^ ((lane >> 3) & 3);
  const ushort* gA = Xb + (size_t)(i0 + (w << 4) + (lane >> 2)) * DD + qs * 8;
  const ushort* gB = Xb + (size_t)(j0 + (w << 4) + (lane >> 2)) * DD + qs * 8;

  f32x4 acc[4][2];
  #pragma unroll
  for (int m = 0; m < 4; ++m)
    #pragma unroll
    for (int n = 0; n < 2; ++n)
      acc[m][n] = (f32x4){0.f, 0.f, 0.f, 0.f};

  #define STAGE(T)                                                             \
    {                                                                          \
      char* bp = LDS + ((T) & 3) * 16384;                                      \
      __builtin_amdgcn_global_load_lds(                                        \
          (const __attribute__((address_space(1))) void*)(gA + (T) * 32),      \
          (__attribute__((address_space(3))) void*)(bp + w * 1024), 16, 0, 0); \
      __builtin_amdgcn_global_load_lds(                                        \
          (const __attribute__((address_space(1))) void*)(gB + (T) * 32),      \
          (__attribute__((address_space(3))) void*)(bp + 8192 + w * 1024), 16, 0, 0); \
    }

  // read-side addresses (constant across tiles): logical k-slot = lane>>4,
  // phys = (lane>>4) ^ ((r>>1)&3) with (r>>1)&3 = ((lane&15)>>1)&3.
  const int rph = ((lane & 15) >> 1) & 3;
  int aoff[4], boff[2];
  #pragma unroll
  for (int m = 0; m < 4; ++m) {
    const int r = (wr << 6) + (m << 4) + (lane & 15);
    aoff[m] = r * 64 + (((lane >> 4) ^ rph) << 4);
  }
  #pragma unroll
  for (int n = 0; n < 2; ++n) {
    const int r = (wc << 5) + (n << 4) + (lane & 15);
    boff[n] = 8192 + r * 64 + (((lane >> 4) ^ rph) << 4);
  }

  // prologue: stage tiles 0,1,2
  STAGE(0) STAGE(1) STAGE(2)

  // main pipeline: t = 0..28, always 3 tiles in flight
  for (int t = 0; t <= NSTEP - 4; ++t) {
    STAGE(t + 3)
    asm volatile("s_waitcnt vmcnt(6)\n\ts_barrier" ::: "memory");
    const char* bp = LDS + (t & 3) * 16384;
    bf16x8 af[4], bfr[2];
    #pragma unroll
    for (int m = 0; m < 4; ++m) af[m] = *(const bf16x8*)(bp + aoff[m]);
    #pragma unroll
    for (int n = 0; n < 2; ++n) bfr[n] = *(const bf16x8*)(bp + boff[n]);
    __builtin_amdgcn_s_setprio(1);
    #pragma unroll
    for (int m = 0; m < 4; ++m)
      #pragma unroll
      for (int n = 0; n < 2; ++n)
        acc[m][n] = __builtin_amdgcn_mfma_f32_16x16x32_bf16(af[m], bfr[n], acc[m][n], 0, 0, 0);
    __builtin_amdgcn_s_setprio(0);
    asm volatile("s_barrier" ::: "memory");
  }
  // tail: drain once, then 3 barrier-free tiles (no more stages -> no WAR)
  asm volatile("s_waitcnt vmcnt(0)\n\ts_barrier" ::: "memory");
  #pragma unroll
  for (int t = NSTEP - 3; t < NSTEP; ++t) {
    const char* bp = LDS + (t & 3) * 16384;
    bf16x8 af[4], bfr[2];
    #pragma unroll
    for (int m = 0; m < 4; ++m) af[m] = *(const bf16x8*)(bp + aoff[m]);
    #pragma unroll
    for (int n = 0; n < 2; ++n) bfr[n] = *(const bf16x8*)(bp + boff[n]);
    #pragma unroll
    for (int m = 0; m < 4; ++m)
      #pragma unroll
      for (int n = 0; n < 2; ++n)
        acc[m][n] = __builtin_amdgcn_mfma_f32_16x16x32_bf16(af[m], bfr[n], acc[m][n], 0, 0, 0);
  }
  __syncthreads();   // all K-loop LDS reads retired before epilogue reuses LDS

  // ---- epilogue (atomic-free, R13 verbatim). C/D map: col=lane&15, row=(lane>>4)*4+reg.
  float* LF = (float*)LDS;         // i-side sfull partials [wc][wr][64] = 512
  float* LM = LF + 512;            // i-side smask
  float* GF = LM + 512;            // j-side sfull [wr][128] = 256
  float* GM = GF + 256;            // j-side smask

  float rnT_j[2];
  unsigned long long wj[2];        // mask row lab[j_n], 64 bits over wave's i-span
  #pragma unroll
  for (int n = 0; n < 2; ++n) {
    const int j = j0 + (wc << 5) + (n << 4) + (lane & 15);
    rnT_j[n] = rnT[j];
    wj[n] = *(const unsigned long long*)(mbits + (size_t)lab[j] * MW + (i0 >> 5) + (wr << 1));
  }
  float pse[2] = {0.f, 0.f}, psm[2] = {0.f, 0.f};

  #pragma unroll
  for (int m = 0; m < 4; ++m) {
    #pragma unroll
    for (int r = 0; r < 4; ++r) {
      const int irow = (m << 4) + ((lane >> 4) << 2) + r;    // 0..63 in wave's row-half
      const int i = i0 + (wr << 6) + irow;
      const float rni = rnx[i];
      const unsigned int wi = mbits[(size_t)lab[i] * MW + (j0 >> 5) + wc];  // wave's 32-col span
      float se = 0.f, sm = 0.f;
      #pragma unroll
      for (int n = 0; n < 2; ++n) {
        const int j = j0 + (wc << 5) + (n << 4) + (lane & 15);
        float e = __expf(acc[m][n][r] * rni * rnT_j[n]);
        if (i == j) e = 0.f;                                 // remove_diag
        se += e;
        const int bposj = (n << 4) + (lane & 15);            // 0..31
        sm += ((wi >> bposj) & 1u) ? e : 0.f;
        pse[n] += e;
        psm[n] += ((wj[n] >> irow) & 1ull) ? e : 0.f;
      }
      #pragma unroll
      for (int off = 1; off < 16; off <<= 1) {
        se += __shfl_xor(se, off);
        sm += __shfl_xor(sm, off);
      }
      if ((lane & 15) == 0) {                                // lanes 0,16,32,48
        LF[(wc << 7) + (wr << 6) + irow] = se;
        LM[(wc << 7) + (wr << 6) + irow] = sm;
      }
    }
  }
  if (offdiag) {
    #pragma unroll
    for (int n = 0; n < 2; ++n) {
      float se = pse[n], sm = psm[n];
      se += __shfl_xor(se, 16); se += __shfl_xor(se, 32);
      sm += __shfl_xor(sm, 16); sm += __shfl_xor(sm, 32);
      if (lane < 16) {
        GF[(wr << 7) + (wc << 5) + (n << 4) + lane] = se;
        GM[(wr << 7) + (wc << 5) + (n << 4) + lane] = sm;
      }
    }
  }
  __syncthreads();

  // cross-wave combine + coalesced stores. Slot ownership:
  //   i-side (rows i0..i0+127) -> slot bx ; j-side (rows j0..j0+127) -> slot by.
  if (tid < 128) {
    scrF[(size_t)bx * NN + i0 + tid] = LF[tid] + LF[128 + tid] + LF[256 + tid] + LF[384 + tid];
    if (offdiag) scrF[(size_t)by * NN + j0 + tid] = GF[tid] + GF[128 + tid];
  } else if (tid < 256) {
    const int u = tid - 128;
    scrM[(size_t)bx * NN + i0 + u] = LM[u] + LM[128 + u] + LM[256 + u] + LM[384 + u];
    if (offdiag) scrM[(size_t)by * NN + j0 + u] = GM[u] + GM[128 + u];
  }
}

// ---------- kernel 3: loss = mean(log(den) - log(num)) ----------
__global__ __launch_bounds__(256) void k_final(
    const float* __restrict__ scrF, const float* __restrict__ scrM,
    const float* __restrict__ epos, float* __restrict__ out) {
  const int idx = blockIdx.x * 256 + threadIdx.x;
  float sf = 0.f, sm = 0.f;
  #pragma unroll
  for (int s = 0; s < SLOTS; ++s) {
    sf += scrF[(size_t)s * NN + idx];
    sm += scrM[(size_t)s * NN + idx];
  }
  const float ep  = epos[idx];
  const float num = sm + ep;
  const float den = ep + sf;
  float v = (logf(den) - logf(num)) * (1.0f / (float)NN);
  #pragma unroll
  for (int off = 32; off > 0; off >>= 1) v += __shfl_down(v, off);
  __shared__ float red[4];
  if ((threadIdx.x & 63) == 0) red[threadIdx.x >> 6] = v;
  __syncthreads();
  if (threadIdx.x == 0) atomicAdd(out, red[0] + red[1] + red[2] + red[3]);
}

extern "C" void kernel_launch(void* const* d_in, const int* in_sizes, int n_in,
                              void* d_out, int out_size, void* d_ws, size_t ws_size,
                              hipStream_t stream) {
  const float* X     = (const float*)d_in[0];
  const float* A     = (const float*)d_in[1];
  const int*   cmask = (const int*)d_in[2];
  const int*   lraw  = (const int*)d_in[3];
  const float* Tp    = (const float*)d_in[4];
  float* out = (float*)d_out;

  char* ws = (char*)d_ws;
  ushort* Xb   = (ushort*)ws;                          // 8 MB
  float* rnx   = (float*)(ws + (size_t)NN * DD * 2);
  float* rnT   = rnx + NN;
  float* epos  = rnT + NN;
  int*   lab   = (int*)(epos + NN);
  unsigned int* mbits = (unsigned int*)(lab + NN);     // 512 KB
  float* scrF  = (float*)(mbits + (size_t)NCLS * MW);  // 512 KB
  float* scrM  = scrF + (size_t)SLOTS * NN;            // 512 KB

  hipLaunchKernelGGL(k_pack,     dim3(NCLS * MW / 256 + NN / 256), dim3(256), 0, stream, cmask, lraw, mbits, lab);
  hipLaunchKernelGGL(k_rowstats, dim3(NN),     dim3(256), 0, stream, X, A, Tp, Xb, rnx, rnT, epos, out);
  hipLaunchKernelGGL(k_gram,     dim3(NTILE),  dim3(512), 0, stream, Xb, rnx, rnT, lab, mbits, scrF, scrM);
  hipLaunchKernelGGL(k_final,    dim3(NN/256), dim3(256), 0, stream, scrF, scrM, epos, out);
}